// Round 7
// baseline (248.818 us; speedup 1.0000x reference)
//
#include <hip/hip_runtime.h>
#include <math.h>

// ---------------------------------------------------------------------------
// Deformable transformer layer, MI355X round-22:
//  - prep_all / gemm_oa_v / deform_fused kept (rounds 10-21).
//  - wp_mlp rebuilt at 32 rows / 512 threads / exactly 80 KB LDS:
//    * 2 blocks/CU -> cross-block overlap hides barrier drains (r21 ran
//      1 block/CU, nothing to overlap with).
//    * guarded amdgpu_num_vgpr(128): kill the allocator's impossible
//      8-waves/EU target that spilled 7 f32/thread (r18/r19/r21).
//    LDS: Q[32][256]f32 XOR-swz (qbuf) | H/QY time-share 32KB | RA 16KB.
//  4 dispatches.
// B=2, Nq=8192, C=256, HEADS=8, dh=32, LEVELS=3, POINTS=4, MLP=4
// ---------------------------------------------------------------------------

typedef short short8 __attribute__((ext_vector_type(8)));
typedef short s16x4 __attribute__((ext_vector_type(4)));
typedef __bf16 bf16x8 __attribute__((ext_vector_type(8)));
typedef float f32x4 __attribute__((ext_vector_type(4)));

#if defined(__has_attribute)
#if __has_attribute(amdgpu_num_vgpr)
#define WPMLP_REGS __attribute__((amdgpu_num_vgpr(128)))
#else
#define WPMLP_REGS
#endif
#else
#define WPMLP_REGS
#endif

__device__ __forceinline__ short f2b(float f) {
  unsigned u = __builtin_bit_cast(unsigned, f);
  u += 0x7fffu + ((u >> 16) & 1u);   // RNE to bf16
  return (short)(u >> 16);
}
__device__ __forceinline__ float b2f(short s) {
  unsigned u = ((unsigned)(unsigned short)s) << 16;
  return __builtin_bit_cast(float, u);
}
__device__ __forceinline__ void b8f(short8 s, float* f) {
  const uint4 u = __builtin_bit_cast(uint4, s);
  f[0] = __builtin_bit_cast(float, u.x << 16);
  f[1] = __builtin_bit_cast(float, u.x & 0xffff0000u);
  f[2] = __builtin_bit_cast(float, u.y << 16);
  f[3] = __builtin_bit_cast(float, u.y & 0xffff0000u);
  f[4] = __builtin_bit_cast(float, u.z << 16);
  f[5] = __builtin_bit_cast(float, u.z & 0xffff0000u);
  f[6] = __builtin_bit_cast(float, u.w << 16);
  f[7] = __builtin_bit_cast(float, u.w & 0xffff0000u);
}

__device__ __forceinline__ f32x4 mfma16(short8 a, short8 b, f32x4 c) {
  return __builtin_amdgcn_mfma_f32_16x16x32_bf16(
      __builtin_bit_cast(bf16x8, a), __builtin_bit_cast(bf16x8, b), c, 0, 0, 0);
}

typedef __attribute__((address_space(3))) unsigned int lds_u32;
typedef const __attribute__((address_space(1))) unsigned int glb_u32;
__device__ __forceinline__ void glds16(const void* g, void* l) {
  __builtin_amdgcn_global_load_lds((glb_u32*)g, (lds_u32*)l, 16, 0, 0);
}

__device__ __forceinline__ float gelu1(float v) {
  return 0.5f * v * (1.f + erff(v * 0.70710678118654752f));
}

// ---------------------------------------------------------------------------
// GEMM core 64x128 tile, BK=64, 24 KB LDS (used by oa/v merged GEMM).
// EPI: 4=oa (bias split 192/96, bf16 out) | 5=bf16+bias
// ---------------------------------------------------------------------------
template <int EPI>
__device__ __forceinline__ void gemm64_core(
    int bx, int by,
    const short* __restrict__ A, const short* __restrict__ Bt,
    const float* __restrict__ bias, const float* __restrict__ bias2,
    void* __restrict__ Cout, int M, int Nreal, int ldc, int K, char* smem)
{
  short* sA = (short*)smem;       // [64][64] shorts (8 KB)
  short* sB = sA + 4096;          // [128][64] shorts (16 KB)
  float* sf = (float*)smem;       // epilogue staging [32][132]

  const int t = threadIdx.x;
  const int wave = t >> 6, lane = t & 63;
  const int quad = lane >> 4, l16 = lane & 15;
  const int wm = (wave & 1) * 32, wn = (wave >> 1) * 64;
  const int m0 = by * 64, n0 = bx * 128;

  f32x4 acc[2][4];
#pragma unroll
  for (int i = 0; i < 2; i++)
#pragma unroll
    for (int j = 0; j < 4; j++) acc[i][j] = (f32x4){0.f, 0.f, 0.f, 0.f};

  const int srow = lane >> 3, pos = lane & 7;
  const int chunk = (pos + srow) & 7;
  const short* gA = A + (size_t)(m0 + wave * 16 + srow) * K + chunk * 8;
  const short* gB = Bt + (size_t)(n0 + wave * 32 + srow) * K + chunk * 8;

  const int nk = K >> 6;
  for (int kt = 0; kt < nk; ++kt) {
    if (kt) __syncthreads();
    const int ko = kt * 64;
#pragma unroll
    for (int g = 0; g < 2; ++g)
      glds16(gA + ko + (size_t)(g * 8) * K, sA + (wave * 16 + g * 8) * 64);
#pragma unroll
    for (int g = 0; g < 4; ++g)
      glds16(gB + ko + (size_t)(g * 8) * K, sB + (wave * 32 + g * 8) * 64);
    __syncthreads();
#pragma unroll
    for (int kk = 0; kk < 2; ++kk) {
      short8 af[2], bf[4];
      const int c = kk * 4 + quad;
#pragma unroll
      for (int i = 0; i < 2; i++) {
        const int lrA = wm + i * 16 + l16;
        af[i] = *(const short8*)&sA[lrA * 64 + ((c - lrA) & 7) * 8];
      }
#pragma unroll
      for (int j = 0; j < 4; j++) {
        const int lrB = wn + j * 16 + l16;
        bf[j] = *(const short8*)&sB[lrB * 64 + ((c - lrB) & 7) * 8];
      }
#pragma unroll
      for (int i = 0; i < 2; i++)
#pragma unroll
        for (int j = 0; j < 4; j++) acc[i][j] = mfma16(bf[j], af[i], acc[i][j]);
    }
  }
  __syncthreads();

  // Epilogue: 2 bands of 32 rows x 128 cols, coalesced full-line stores.
#pragma unroll
  for (int b = 0; b < 2; ++b) {
    if (wm == b * 32) {
#pragma unroll
      for (int i = 0; i < 2; ++i) {
        const int rr = i * 16 + l16;
#pragma unroll
        for (int j = 0; j < 4; ++j)
          *(f32x4*)&sf[rr * 132 + wn + quad * 4 + j * 16] = acc[i][j];
      }
    }
    __syncthreads();
#pragma unroll
    for (int r2 = 0; r2 < 4; ++r2) {
      const int fidx = r2 * 1024 + t * 4;
      const int row = fidx >> 7, col = fidx & 127;
      const int gm = m0 + b * 32 + row;
      const int cc = n0 + col;
      if (gm < M && cc < Nreal) {
        const float4 v = *(const float4*)&sf[row * 132 + col];
        float4 bb;
        if (EPI == 4) bb = (cc < 192) ? *(const float4*)(bias + cc)
                                      : *(const float4*)(bias2 + cc - 192);
        else bb = *(const float4*)(bias + cc);
        float v0 = v.x + bb.x, v1 = v.y + bb.y, v2 = v.z + bb.z, v3 = v.w + bb.w;
        s16x4 o; o.x = f2b(v0); o.y = f2b(v1); o.z = f2b(v2); o.w = f2b(v3);
        *(s16x4*)((short*)Cout + (size_t)gm * ldc + cc) = o;
      }
    }
    __syncthreads();
  }
}

// Merged: blocks [0,768) -> oa GEMM (EPI4, bf16 out), [768,1162) -> v (EPI5)
__global__ __launch_bounds__(256) void gemm_oa_v(
    const short* __restrict__ qa, const short* __restrict__ wt_oa,
    const float* __restrict__ bo, const float* __restrict__ ba,
    short* __restrict__ oabuf,
    const short* __restrict__ valbf, const short* __restrict__ wt_v,
    const float* __restrict__ bv, short* __restrict__ vproj)
{
  __shared__ __align__(16) char smem[24576];
  const int idx = blockIdx.x;
  if (idx < 768) {
    gemm64_core<4>(idx % 3, idx / 3, qa, wt_oa, bo, ba,
                   oabuf, 16384, 288, 288, 256, smem);
  } else {
    const int r = idx - 768;
    gemm64_core<5>(r % 2, r / 2, valbf, wt_v, bv, nullptr,
                   vproj, 12600, 256, 256, 256, smem);
  }
}

// ---------------------------------------------------------------------------
// wp_mlp: per 32-row block (grid 512, 512 threads, 80 KB LDS, 2 blocks/CU):
//   Q  = sampled@Wp (XOR-swz) -> qbuf in-place (LDS)
//   RA = sampled (rotated) -> q2 (rotated)
//   H/QY time-share: query f32 staging -> H-halves -> final staging
//   out = Q + H@Wf2 + bf2
// ---------------------------------------------------------------------------
__global__ __launch_bounds__(512) WPMLP_REGS void wp_mlp(
    const short* __restrict__ sampled,  // [16384][256] bf16
    const short* __restrict__ wtp,      // frag-major K=256 N=256
    const float* __restrict__ bp,
    const short* __restrict__ qnb,      // [16384][256] bf16
    const float* __restrict__ query,    // [16384][256] f32
    const float* __restrict__ g2, const float* __restrict__ b2v,
    const short* __restrict__ wf1,      // frag-major K=256 N=1024
    const float* __restrict__ b1v,
    const short* __restrict__ wf2,      // frag-major K=1024 N=256
    const float* __restrict__ bf2v,
    float* __restrict__ outp)           // [16384][256] f32
{
  __shared__ __align__(16) char smem[81920];
  float* Q  = (float*)smem;             // [32][256] f32, XOR-swz (32 KB)
  short* H  = (short*)(smem + 32768);   // [32][512] bf16 H-half (rotated)
  float* QY = (float*)(smem + 32768);   // query staging / final staging
  short* RA = (short*)(smem + 65536);   // [32][256] bf16 rotated (16 KB)

  const int t = threadIdx.x;
  const int w = t >> 6, lane = t & 63;
  const int quad = lane >> 4, l16 = lane & 15;
  const int wm2 = w >> 2, wn4 = w & 3;   // 2M x 4N wave grid
  const int m0 = blockIdx.x * 32;

  // ---- stage sampled -> RA (rotated, 2/thread) + query -> QY (4/thread) --
#pragma unroll
  for (int q = 0; q < 2; ++q) {
    const int g = q * 512 + t;
    const int row = g >> 5, p = g & 31;
    const int cl = (p & ~7) | ((p + row) & 7);
    glds16(sampled + (size_t)(m0 + row) * 256 + cl * 8,
           RA + (q * 512 + w * 64) * 8);
  }
#pragma unroll
  for (int q = 0; q < 4; ++q) {
    const int g = q * 512 + t;
    glds16(query + (size_t)(m0 + (g >> 6)) * 256 + (g & 63) * 4,
           QY + (q * 512 + w * 64) * 4);
  }
  __syncthreads();

  // ---- wp GEMM: acc[4], K=256 (32 chunks), no barriers ------------------
  {
    f32x4 accp[4];
#pragma unroll
    for (int j = 0; j < 4; j++) accp[j] = (f32x4){0.f, 0.f, 0.f, 0.f};
#pragma unroll
    for (int kk = 0; kk < 8; ++kk) {
      const int c = kk * 4 + quad;
      const int r = wm2 * 16 + l16;
      const int pos = (c & ~7) | ((c - r) & 7);
      const short8 afr = *(const short8*)(RA + r * 256 + pos * 8);
      short8 bfr[4];
#pragma unroll
      for (int j = 0; j < 4; ++j) {
        const int n1 = wn4 * 4 + j;
        bfr[j] = *(const short8*)(wtp + ((size_t)n1 * 32 + c) * 128 + l16 * 8);
      }
#pragma unroll
      for (int j = 0; j < 4; ++j) accp[j] = mfma16(bfr[j], afr, accp[j]);
    }
    // stage wp acc into Q (XOR-swz: col ^ ((row&7)<<2))
#pragma unroll
    for (int j = 0; j < 4; ++j) {
      const int r = wm2 * 16 + l16;
      const int c = wn4 * 64 + j * 16 + quad * 4;
      *(f32x4*)&Q[r * 256 + (c ^ ((r & 7) << 2))] = accp[j];
    }
  }
  __syncthreads();   // Q (wp acc) + QY (query) ready; RA reads done

  // ---- LN2: wave w owns rows {w, 8+w, 16+w, 24+w}; qbuf in-place in Q ----
  {
    const float4 bbp  = *(const float4*)(bp + lane * 4);
    const float4 gv   = *(const float4*)(g2 + lane * 4);
    const float4 bb2  = *(const float4*)(b2v + lane * 4);
#pragma unroll
    for (int rep = 0; rep < 4; ++rep) {
      const int row = rep * 8 + w;
      const int gm = m0 + row;
      const int cs = (lane * 4) ^ ((row & 7) << 2);
      const float4 a  = *(const float4*)&Q[row * 256 + cs];
      const float4 qv = *(const float4*)&QY[row * 256 + lane * 4];
      const s16x4 qn  = *(const s16x4*)(qnb + (size_t)gm * 256 + lane * 4);
      float v0 = a.x + bbp.x + b2f(qn.x) + qv.x;
      float v1 = a.y + bbp.y + b2f(qn.y) + qv.y;
      float v2 = a.z + bbp.z + b2f(qn.z) + qv.z;
      float v3 = a.w + bbp.w + b2f(qn.w) + qv.w;
      float s = v0 + v1 + v2 + v3;
#pragma unroll
      for (int o = 32; o; o >>= 1) s += __shfl_xor(s, o);
      const float mean = s * (1.f / 256.f);
      const float d0 = v0 - mean, d1 = v1 - mean, d2 = v2 - mean, d3 = v3 - mean;
      float ss = d0 * d0 + d1 * d1 + d2 * d2 + d3 * d3;
#pragma unroll
      for (int o = 32; o; o >>= 1) ss += __shfl_xor(ss, o);
      const float inv = rsqrtf(ss * (1.f / 256.f) + 1e-5f);
      *(f32x4*)&Q[row * 256 + cs] = (f32x4){v0, v1, v2, v3};  // qbuf
      const int col = lane * 4;
      const int c = col >> 3;
      const int pos = (c & ~7) | ((c - row) & 7);
      s16x4 o2;
      o2.x = f2b(d0 * inv * gv.x + bb2.x);
      o2.y = f2b(d1 * inv * gv.y + bb2.y);
      o2.z = f2b(d2 * inv * gv.z + bb2.z);
      o2.w = f2b(d3 * inv * gv.w + bb2.w);
      *(s16x4*)(RA + row * 256 + pos * 8 + (col & 7)) = o2;
    }
  }
  __syncthreads();   // RA = q2 ready; QY (query) dead -> region becomes H

  // ---- MLP in two 512-col halves of H ------------------------------------
  f32x4 acc2[4];
#pragma unroll
  for (int j = 0; j < 4; j++) acc2[j] = (f32x4){0.f, 0.f, 0.f, 0.f};

  for (int h = 0; h < 2; ++h) {
    if (h) __syncthreads();            // prior H-half reads done
    // phase-1: H-half = gelu(q2 @ Wf1[:, h*512:+512] + b1)
    f32x4 acc1[8];
#pragma unroll
    for (int j = 0; j < 8; j++) acc1[j] = (f32x4){0.f, 0.f, 0.f, 0.f};
#pragma unroll
    for (int kk = 0; kk < 8; ++kk) {
      const int cg = kk * 4 + quad;
      const int r = wm2 * 16 + l16;
      const int pos = (cg & ~7) | ((cg - r) & 7);
      const short8 afr = *(const short8*)(RA + r * 256 + pos * 8);
      short8 bfr[8];
#pragma unroll
      for (int j = 0; j < 8; ++j) {
        const int n1 = h * 32 + wn4 * 8 + j;
        bfr[j] = *(const short8*)(wf1 + ((size_t)n1 * 32 + cg) * 128 + l16 * 8);
      }
#pragma unroll
      for (int j = 0; j < 8; ++j) acc1[j] = mfma16(bfr[j], afr, acc1[j]);
    }
    // bias + gelu -> bf16 -> H-half (rotated)
#pragma unroll
    for (int j = 0; j < 8; ++j) {
      const int coll = wn4 * 128 + j * 16 + quad * 4;   // local col [0,512)
      const float4 bb = *(const float4*)(b1v + h * 512 + coll);
      const int c = coll >> 3;
      const int r = wm2 * 16 + l16;
      const int pos = (c & ~7) | ((c - r) & 7);
      s16x4 o;
      o.x = f2b(gelu1(acc1[j].x + bb.x));
      o.y = f2b(gelu1(acc1[j].y + bb.y));
      o.z = f2b(gelu1(acc1[j].z + bb.z));
      o.w = f2b(gelu1(acc1[j].w + bb.w));
      *(s16x4*)(H + r * 512 + pos * 8 + (coll & 7)) = o;
    }
    __syncthreads();                   // H-half complete

    // phase-2: acc2 += H-half @ Wf2[h*512:+512, :]
#pragma unroll 4
    for (int kk = 0; kk < 16; ++kk) {
      const int cl = kk * 4 + quad;    // local chunk [0,64)
      const int r = wm2 * 16 + l16;
      const int pos = (cl & ~7) | ((cl - r) & 7);
      const short8 afr = *(const short8*)(H + r * 512 + pos * 8);
      short8 bfr[4];
#pragma unroll
      for (int j = 0; j < 4; ++j) {
        const int n1 = wn4 * 4 + j;
        bfr[j] = *(const short8*)(wf2 + ((size_t)n1 * 128 + h * 64 + cl) * 128 + l16 * 8);
      }
#pragma unroll
      for (int j = 0; j < 4; ++j) acc2[j] = mfma16(bfr[j], afr, acc2[j]);
    }
  }
  __syncthreads();   // all H reads done; H region becomes f32 staging

#pragma unroll
  for (int j = 0; j < 4; ++j) {
    const int r = wm2 * 16 + l16;
    const int c = wn4 * 64 + j * 16 + quad * 4;
    *(f32x4*)&QY[r * 256 + (c ^ ((r & 7) << 2))] = acc2[j];
  }
  __syncthreads();

  {
    const float4 bbf = *(const float4*)(bf2v + lane * 4);
#pragma unroll
    for (int rep = 0; rep < 4; ++rep) {
      const int row = rep * 8 + w;
      const int gm = m0 + row;
      const int cs = (lane * 4) ^ ((row & 7) << 2);
      const float4 v  = *(const float4*)&QY[row * 256 + cs];
      const float4 qb = *(const float4*)&Q[row * 256 + cs];
      *(float4*)(outp + (size_t)gm * 256 + lane * 4) =
          make_float4(v.x + bbf.x + qb.x, v.y + bbf.y + qb.y,
                      v.z + bbf.z + qb.z, v.w + bbf.w + qb.w);
    }
  }
}

// ---------------------------------------------------------------------------
// prep_all: merged wconvert (1792 blocks) + vconvert (3169) + LN1 (4096).
// Wp/Wf1/Wf2 packed FRAGMENT-MAJOR for direct-global B loads.
// ---------------------------------------------------------------------------
__global__ __launch_bounds__(256) void prep_all(
    const float* __restrict__ Wo, const float* __restrict__ Wa,
    const float* __restrict__ Wv, const float* __restrict__ Wp,
    const float* __restrict__ Wf1, const float* __restrict__ Wf2,
    short* __restrict__ t_oa, short* __restrict__ t_v, short* __restrict__ t_p,
    short* __restrict__ t_f1, short* __restrict__ t_f2,
    const float* __restrict__ value, short* __restrict__ valbf,
    const float* __restrict__ query, const float* __restrict__ query_pos,
    const float* __restrict__ g1, const float* __restrict__ b1,
    short* __restrict__ qnb, short* __restrict__ qa)
{
  __shared__ float tile[32][33];
  const int t = threadIdx.x;
  const int blk = blockIdx.x;

  if (blk < 1792) {
    const int bxa = blk & 255, bya = blk >> 8;
    int K, N, noff; const float* src; short* dst;
    switch (bya) {
      case 0: src = Wo;      dst = t_oa; K = 256;  N = 192;  noff = 0;   break;
      case 1: src = Wa;      dst = t_oa; K = 256;  N = 96;   noff = 192; break;
      case 2: src = nullptr; dst = t_oa; K = 256;  N = 96;   noff = 288; break;
      case 3: src = Wv;      dst = t_v;  K = 256;  N = 256;  noff = 0;   break;
      case 4: src = Wp;      dst = t_p;  K = 256;  N = 256;  noff = 0;   break;
      case 5: src = Wf1;     dst = t_f1; K = 256;  N = 1024; noff = 0;   break;
      default: src = Wf2;    dst = t_f2; K = 1024; N = 256;  noff = 0;   break;
    }
    const bool fragpack = (bya >= 4);
    const int tilesK = K >> 5;
    const int nt = tilesK * (N >> 5);
    if (bxa >= nt) return;
    const int tk = bxa % tilesK, tn = bxa / tilesK;
    const int k0 = tk * 32, n0 = tn * 32;
    const int r = t >> 3, c4 = (t & 7) * 4;
    float4 v = make_float4(0.f, 0.f, 0.f, 0.f);
    if (src) v = *(const float4*)(src + (size_t)(k0 + r) * N + n0 + c4);
    tile[r][c4] = v.x; tile[r][c4 + 1] = v.y; tile[r][c4 + 2] = v.z; tile[r][c4 + 3] = v.w;
    __syncthreads();
    const int nn = t >> 3, kc = (t & 7) * 4;
    s16x4 o;
    o.x = f2b(tile[kc][nn]); o.y = f2b(tile[kc + 1][nn]);
    o.z = f2b(tile[kc + 2][nn]); o.w = f2b(tile[kc + 3][nn]);
    if (fragpack) {
      const int n = n0 + nn, k = k0 + kc;
      *(s16x4*)(dst + ((size_t)(n >> 4) * (K >> 3) + (k >> 3)) * 128 +
                (n & 15) * 8 + (k & 7)) = o;
    } else {
      *(s16x4*)(dst + (size_t)(noff + n0 + nn) * K + k0 + kc) = o;
    }
  } else if (blk < 1792 + 3169) {
    const int i = ((blk - 1792) * 256 + t) * 4;
    if (i >= 12672 * 256) return;
    s16x4 o = (s16x4){0, 0, 0, 0};
    if (i < 12600 * 256) {
      float4 v = *(const float4*)(value + i);
      o.x = f2b(v.x); o.y = f2b(v.y); o.z = f2b(v.z); o.w = f2b(v.w);
    }
    *(s16x4*)(valbf + i) = o;
  } else {
    const int row  = (blk - 4961) * 4 + (t >> 6);
    const int lane = t & 63;
    const float4 v = ((const float4*)(query + (size_t)row * 256))[lane];
    float s = v.x + v.y + v.z + v.w;
#pragma unroll
    for (int o = 32; o; o >>= 1) s += __shfl_xor(s, o);
    const float mean = s * (1.f / 256.f);
    const float dx = v.x - mean, dy = v.y - mean, dz = v.z - mean, dw = v.w - mean;
    float s2 = dx * dx + dy * dy + dz * dz + dw * dw;
#pragma unroll
    for (int o = 32; o; o >>= 1) s2 += __shfl_xor(s2, o);
    const float inv = rsqrtf(s2 * (1.f / 256.f) + 1e-5f);
    const float4 gv = ((const float4*)g1)[lane];
    const float4 bv = ((const float4*)b1)[lane];
    const float4 o1 = make_float4(dx * inv * gv.x + bv.x, dy * inv * gv.y + bv.y,
                                  dz * inv * gv.z + bv.z, dw * inv * gv.w + bv.w);
    s16x4 ob; ob.x = f2b(o1.x); ob.y = f2b(o1.y); ob.z = f2b(o1.z); ob.w = f2b(o1.w);
    ((s16x4*)(qnb + (size_t)row * 256))[lane] = ob;
    const float4 pv = ((const float4*)(query_pos + (size_t)row * 256))[lane];
    s16x4 op;
    op.x = f2b(o1.x + pv.x); op.y = f2b(o1.y + pv.y);
    op.z = f2b(o1.z + pv.z); op.w = f2b(o1.w + pv.w);
    ((s16x4*)(qa + (size_t)row * 256))[lane] = op;
  }
}

// ---------------------------------------------------------------------------
// deform_fused: block = 8 rows. Phase 1 (64 threads): softmax + bilinear
// setup -> LDS tables (oa bf16). Phase 2 (256 threads): gather+FMA.
// ---------------------------------------------------------------------------
__global__ __launch_bounds__(256) void deform_fused(
    const short* __restrict__ vproj, const short* __restrict__ oa,
    const float* __restrict__ refp, short* __restrict__ out)
{
  __shared__ int4 sIdx[768];
  __shared__ s16x4 sW[768];
  const int t = threadIdx.x;

  if (t < 64) {
    const int row = blockIdx.x * 8 + (t >> 3), h = t & 7;
    const short* oarow = oa + (size_t)row * 288;
    float off[24];
    {
      const short8* op = (const short8*)(oarow + h * 24);  // 48 B, 16B-aligned
      b8f(op[0], off); b8f(op[1], off + 8); b8f(op[2], off + 16);
    }
    float lg[12];
    {
      const s16x4* ap = (const s16x4*)(oarow + 192 + h * 12);  // 8B-aligned
#pragma unroll
      for (int i = 0; i < 3; i++) {
        const s16x4 v = ap[i];
        lg[i * 4] = b2f(v.x); lg[i * 4 + 1] = b2f(v.y);
        lg[i * 4 + 2] = b2f(v.z); lg[i * 4 + 3] = b2f(v.w);
      }
    }
    const float* rp = refp + (size_t)row * 6;
    const float Rx[3] = {rp[0], rp[2], rp[4]}, Ry[3] = {rp[1], rp[3], rp[5]};
    float mx = lg[0];
#pragma unroll
    for (int i = 1; i < 12; i++) mx = fmaxf(mx, lg[i]);
    float sum = 0.f;
#pragma unroll
    for (int i = 0; i < 12; i++) { lg[i] = __expf(lg[i] - mx); sum += lg[i]; }
    const float inv = 1.f / sum;
    const int b = row >> 13;
    const int Hs[3] = {60, 30, 15}, Ws[3] = {80, 40, 20}, St[3] = {0, 4800, 6000};
#pragma unroll
    for (int p = 0; p < 12; p++) {
      const int l = p >> 2;
      const int W = Ws[l], H = Hs[l];
      const float gx = Rx[l] * W + off[p * 2]     - 0.5f;
      const float gy = Ry[l] * H + off[p * 2 + 1] - 0.5f;
      const float x0f = floorf(gx), y0f = floorf(gy);
      const float wx = gx - x0f, wy = gy - y0f;
      const int x0 = (int)x0f, y0 = (int)y0f;
      const float aw = lg[p] * inv;
      float cw[4] = {(1.f - wx) * (1.f - wy), wx * (1.f - wy),
                     (1.f - wx) * wy, wx * wy};
      const int base = b * 6300 + St[l];
      int ci[4];
#pragma unroll
      for (int k = 0; k < 4; k++) {
        const int xx = x0 + (k & 1), yy = y0 + (k >> 1);
        const bool valid = (xx >= 0) & (xx < W) & (yy >= 0) & (yy < H);
        const int xc = min(max(xx, 0), W - 1);
        const int yc = min(max(yy, 0), H - 1);
        ci[k] = ((base + yc * W + xc) << 8) + h * 32;
        cw[k] = valid ? cw[k] * aw : 0.f;
      }
      sIdx[t * 12 + p] = make_int4(ci[0], ci[1], ci[2], ci[3]);
      s16x4 wv; wv.x = f2b(cw[0]); wv.y = f2b(cw[1]); wv.z = f2b(cw[2]); wv.w = f2b(cw[3]);
      sW[t * 12 + p] = wv;
    }
  }
  __syncthreads();

  const int lu = t >> 2, c4 = (t & 3) * 8;
  float acc[8];
#pragma unroll
  for (int i = 0; i < 8; i++) acc[i] = 0.f;
#pragma unroll 2
  for (int p = 0; p < 12; p++) {
    const int4 idx = sIdx[lu * 12 + p];
    const s16x4 wb = sW[lu * 12 + p];
    const float w0 = b2f(wb.x), w1 = b2f(wb.y), w2 = b2f(wb.z), w3 = b2f(wb.w);
    const short8 v0 = *(const short8*)(vproj + idx.x + c4);
    const short8 v1 = *(const short8*)(vproj + idx.y + c4);
    const short8 v2 = *(const short8*)(vproj + idx.z + c4);
    const short8 v3 = *(const short8*)(vproj + idx.w + c4);
    float f0[8], f1[8], f2[8], f3[8];
    b8f(v0, f0); b8f(v1, f1); b8f(v2, f2); b8f(v3, f3);
#pragma unroll
    for (int j = 0; j < 8; j++)
      acc[j] += w0 * f0[j] + w1 * f1[j] + w2 * f2[j] + w3 * f3[j];
  }
  short8 o;
#pragma unroll
  for (int j = 0; j < 8; j++) o[j] = f2b(acc[j]);
  *(short8*)(out + (size_t)(blockIdx.x * 256 + t) * 8) = o;
}

// ---------------------------------------------------------------------------
// Launch
// ---------------------------------------------------------------------------
extern "C" void kernel_launch(void* const* d_in, const int* in_sizes, int n_in,
                              void* d_out, int out_size, void* d_ws, size_t ws_size,
                              hipStream_t stream)
{
  const float* query     = (const float*)d_in[0];
  const float* value     = (const float*)d_in[1];
  const float* query_pos = (const float*)d_in[2];
  const float* ref_pts   = (const float*)d_in[3];
  const float* g1  = (const float*)d_in[6];
  const float* b1  = (const float*)d_in[7];
  const float* Wo  = (const float*)d_in[8];
  const float* bo  = (const float*)d_in[9];
  const float* Wa  = (const float*)d_in[10];
  const float* ba  = (const float*)d_in[11];
  const float* Wv  = (const float*)d_in[12];
  const float* bv  = (const float*)d_in[13];
  const float* Wp  = (const float*)d_in[14];
  const float* bp  = (const float*)d_in[15];
  const float* g2  = (const float*)d_in[16];
  const float* b2  = (const float*)d_in[17];
  const float* Wf1 = (const float*)d_in[18];
  const float* bf1 = (const float*)d_in[19];
  const float* Wf2 = (const float*)d_in[20];
  const float* bf2 = (const float*)d_in[21];

  char* ws = (char*)d_ws;
  short* wt_oa   = (short*)(ws + 0);          // 384x256 bf16
  short* wt_v    = (short*)(ws + 196608);
  short* wt_p    = (short*)(ws + 327680);     // frag-major packed
  short* wt_f1   = (short*)(ws + 458752);     // frag-major packed
  short* wt_f2   = (short*)(ws + 983040);     // frag-major packed
  short* qnb     = (short*)(ws + 1507328);    // 16384x256 bf16 (LN1, no pos)
  short* qa      = (short*)(ws + 18284544);   // 16384x256 bf16
  short* oabuf   = (short*)(ws + 26673152);   // 16384x288 bf16 (9.4 MB)
  short* vproj   = (short*)(ws + 45547520);   // 12600x256 bf16
  short* sampled = (short*)(ws + 51998720);   // 16384x256 bf16
  short* valbf   = (short*)(ws + 77164544);   // 12672x256 bf16
  float* outp = (float*)d_out;

  // 1. merged: weight convert/pack + value convert + LN1
  prep_all<<<9057, 256, 0, stream>>>(Wo, Wa, Wv, Wp, Wf1, Wf2,
                                     wt_oa, wt_v, wt_p, wt_f1, wt_f2,
                                     value, valbf, query, query_pos,
                                     g1, b1, qnb, qa);
  // 2. merged GEMMs: oa (768 blocks, bf16 out) + vproj (394 blocks)
  gemm_oa_v<<<1162, 256, 0, stream>>>(qa, wt_oa, bo, ba, oabuf,
                                      valbf, wt_v, bv, vproj);
  // 3. fused prep+gather -> sampled bf16
  deform_fused<<<2048, 256, 0, stream>>>(vproj, oabuf, ref_pts, sampled);
  // 4. merged Wp-GEMM + LN2 + MLP (32-row blocks, 2 blocks/CU, no spill)
  wp_mlp<<<512, 512, 0, stream>>>(sampled, wt_p, bp, qnb, query, g2, b2,
                                  wt_f1, bf1, wt_f2, bf2, outp);
}

// Round 8
// 219.617 us; speedup vs baseline: 1.1330x; 1.1330x over previous
//
#include <hip/hip_runtime.h>
#include <math.h>

// ---------------------------------------------------------------------------
// Deformable transformer layer, MI355X round-23:
//  - prep_all / gemm_oa_v / deform_fused kept (rounds 10-22).
//  - wp_mlp: round-22's 80 KB block could NOT co-schedule (2x80 = exactly
//    160 KB pool -> 1 block/CU, 8 waves, dur doubled). Now 64 KB LDS:
//    * no query staging (direct global reads in LN2; 2nd block hides latency)
//    * H in four 256-col quarters (16 KB)
//    * final add done IN PLACE in Q (fragment-owned) -> no f32 staging region
//    2 blocks/CU = 16 waves/CU, zero spill, grid 512.
//  4 dispatches.
// B=2, Nq=8192, C=256, HEADS=8, dh=32, LEVELS=3, POINTS=4, MLP=4
// ---------------------------------------------------------------------------

typedef short short8 __attribute__((ext_vector_type(8)));
typedef short s16x4 __attribute__((ext_vector_type(4)));
typedef __bf16 bf16x8 __attribute__((ext_vector_type(8)));
typedef float f32x4 __attribute__((ext_vector_type(4)));

#if defined(__has_attribute)
#if __has_attribute(amdgpu_num_vgpr)
#define WPMLP_REGS __attribute__((amdgpu_num_vgpr(128)))
#else
#define WPMLP_REGS
#endif
#else
#define WPMLP_REGS
#endif

__device__ __forceinline__ short f2b(float f) {
  unsigned u = __builtin_bit_cast(unsigned, f);
  u += 0x7fffu + ((u >> 16) & 1u);   // RNE to bf16
  return (short)(u >> 16);
}
__device__ __forceinline__ float b2f(short s) {
  unsigned u = ((unsigned)(unsigned short)s) << 16;
  return __builtin_bit_cast(float, u);
}
__device__ __forceinline__ void b8f(short8 s, float* f) {
  const uint4 u = __builtin_bit_cast(uint4, s);
  f[0] = __builtin_bit_cast(float, u.x << 16);
  f[1] = __builtin_bit_cast(float, u.x & 0xffff0000u);
  f[2] = __builtin_bit_cast(float, u.y << 16);
  f[3] = __builtin_bit_cast(float, u.y & 0xffff0000u);
  f[4] = __builtin_bit_cast(float, u.z << 16);
  f[5] = __builtin_bit_cast(float, u.z & 0xffff0000u);
  f[6] = __builtin_bit_cast(float, u.w << 16);
  f[7] = __builtin_bit_cast(float, u.w & 0xffff0000u);
}

__device__ __forceinline__ f32x4 mfma16(short8 a, short8 b, f32x4 c) {
  return __builtin_amdgcn_mfma_f32_16x16x32_bf16(
      __builtin_bit_cast(bf16x8, a), __builtin_bit_cast(bf16x8, b), c, 0, 0, 0);
}

typedef __attribute__((address_space(3))) unsigned int lds_u32;
typedef const __attribute__((address_space(1))) unsigned int glb_u32;
__device__ __forceinline__ void glds16(const void* g, void* l) {
  __builtin_amdgcn_global_load_lds((glb_u32*)g, (lds_u32*)l, 16, 0, 0);
}

__device__ __forceinline__ float gelu1(float v) {
  return 0.5f * v * (1.f + erff(v * 0.70710678118654752f));
}

// ---------------------------------------------------------------------------
// GEMM core 64x128 tile, BK=64, 24 KB LDS (used by oa/v merged GEMM).
// EPI: 4=oa (bias split 192/96, bf16 out) | 5=bf16+bias
// ---------------------------------------------------------------------------
template <int EPI>
__device__ __forceinline__ void gemm64_core(
    int bx, int by,
    const short* __restrict__ A, const short* __restrict__ Bt,
    const float* __restrict__ bias, const float* __restrict__ bias2,
    void* __restrict__ Cout, int M, int Nreal, int ldc, int K, char* smem)
{
  short* sA = (short*)smem;       // [64][64] shorts (8 KB)
  short* sB = sA + 4096;          // [128][64] shorts (16 KB)
  float* sf = (float*)smem;       // epilogue staging [32][132]

  const int t = threadIdx.x;
  const int wave = t >> 6, lane = t & 63;
  const int quad = lane >> 4, l16 = lane & 15;
  const int wm = (wave & 1) * 32, wn = (wave >> 1) * 64;
  const int m0 = by * 64, n0 = bx * 128;

  f32x4 acc[2][4];
#pragma unroll
  for (int i = 0; i < 2; i++)
#pragma unroll
    for (int j = 0; j < 4; j++) acc[i][j] = (f32x4){0.f, 0.f, 0.f, 0.f};

  const int srow = lane >> 3, pos = lane & 7;
  const int chunk = (pos + srow) & 7;
  const short* gA = A + (size_t)(m0 + wave * 16 + srow) * K + chunk * 8;
  const short* gB = Bt + (size_t)(n0 + wave * 32 + srow) * K + chunk * 8;

  const int nk = K >> 6;
  for (int kt = 0; kt < nk; ++kt) {
    if (kt) __syncthreads();
    const int ko = kt * 64;
#pragma unroll
    for (int g = 0; g < 2; ++g)
      glds16(gA + ko + (size_t)(g * 8) * K, sA + (wave * 16 + g * 8) * 64);
#pragma unroll
    for (int g = 0; g < 4; ++g)
      glds16(gB + ko + (size_t)(g * 8) * K, sB + (wave * 32 + g * 8) * 64);
    __syncthreads();
#pragma unroll
    for (int kk = 0; kk < 2; ++kk) {
      short8 af[2], bf[4];
      const int c = kk * 4 + quad;
#pragma unroll
      for (int i = 0; i < 2; i++) {
        const int lrA = wm + i * 16 + l16;
        af[i] = *(const short8*)&sA[lrA * 64 + ((c - lrA) & 7) * 8];
      }
#pragma unroll
      for (int j = 0; j < 4; j++) {
        const int lrB = wn + j * 16 + l16;
        bf[j] = *(const short8*)&sB[lrB * 64 + ((c - lrB) & 7) * 8];
      }
#pragma unroll
      for (int i = 0; i < 2; i++)
#pragma unroll
        for (int j = 0; j < 4; j++) acc[i][j] = mfma16(bf[j], af[i], acc[i][j]);
    }
  }
  __syncthreads();

  // Epilogue: 2 bands of 32 rows x 128 cols, coalesced full-line stores.
#pragma unroll
  for (int b = 0; b < 2; ++b) {
    if (wm == b * 32) {
#pragma unroll
      for (int i = 0; i < 2; ++i) {
        const int rr = i * 16 + l16;
#pragma unroll
        for (int j = 0; j < 4; ++j)
          *(f32x4*)&sf[rr * 132 + wn + quad * 4 + j * 16] = acc[i][j];
      }
    }
    __syncthreads();
#pragma unroll
    for (int r2 = 0; r2 < 4; ++r2) {
      const int fidx = r2 * 1024 + t * 4;
      const int row = fidx >> 7, col = fidx & 127;
      const int gm = m0 + b * 32 + row;
      const int cc = n0 + col;
      if (gm < M && cc < Nreal) {
        const float4 v = *(const float4*)&sf[row * 132 + col];
        float4 bb;
        if (EPI == 4) bb = (cc < 192) ? *(const float4*)(bias + cc)
                                      : *(const float4*)(bias2 + cc - 192);
        else bb = *(const float4*)(bias + cc);
        float v0 = v.x + bb.x, v1 = v.y + bb.y, v2 = v.z + bb.z, v3 = v.w + bb.w;
        s16x4 o; o.x = f2b(v0); o.y = f2b(v1); o.z = f2b(v2); o.w = f2b(v3);
        *(s16x4*)((short*)Cout + (size_t)gm * ldc + cc) = o;
      }
    }
    __syncthreads();
  }
}

// Merged: blocks [0,768) -> oa GEMM (EPI4, bf16 out), [768,1162) -> v (EPI5)
__global__ __launch_bounds__(256) void gemm_oa_v(
    const short* __restrict__ qa, const short* __restrict__ wt_oa,
    const float* __restrict__ bo, const float* __restrict__ ba,
    short* __restrict__ oabuf,
    const short* __restrict__ valbf, const short* __restrict__ wt_v,
    const float* __restrict__ bv, short* __restrict__ vproj)
{
  __shared__ __align__(16) char smem[24576];
  const int idx = blockIdx.x;
  if (idx < 768) {
    gemm64_core<4>(idx % 3, idx / 3, qa, wt_oa, bo, ba,
                   oabuf, 16384, 288, 288, 256, smem);
  } else {
    const int r = idx - 768;
    gemm64_core<5>(r % 2, r / 2, valbf, wt_v, bv, nullptr,
                   vproj, 12600, 256, 256, 256, smem);
  }
}

// ---------------------------------------------------------------------------
// wp_mlp: per 32-row block (grid 512, 512 threads, 64 KB LDS, 2 blocks/CU):
//   Q  = sampled@Wp (XOR-swz) -> qbuf in-place -> final out in-place
//   RA = sampled (rotated) -> q2 (rotated)
//   H  = one 256-col quarter of hidden (rotated), 4 quarters total
//   out = Q (qbuf + H@Wf2 + bf2, accumulated in place)
// ---------------------------------------------------------------------------
__global__ __launch_bounds__(512) WPMLP_REGS void wp_mlp(
    const short* __restrict__ sampled,  // [16384][256] bf16
    const short* __restrict__ wtp,      // frag-major K=256 N=256
    const float* __restrict__ bp,
    const short* __restrict__ qnb,      // [16384][256] bf16
    const float* __restrict__ query,    // [16384][256] f32
    const float* __restrict__ g2, const float* __restrict__ b2v,
    const short* __restrict__ wf1,      // frag-major K=256 N=1024
    const float* __restrict__ b1v,
    const short* __restrict__ wf2,      // frag-major K=1024 N=256
    const float* __restrict__ bf2v,
    float* __restrict__ outp)           // [16384][256] f32
{
  __shared__ __align__(16) char smem[65536];
  float* Q  = (float*)smem;             // [32][256] f32, XOR-swz (32 KB)
  short* H  = (short*)(smem + 32768);   // [32][256] bf16 quarter (16 KB)
  short* RA = (short*)(smem + 49152);   // [32][256] bf16 rotated (16 KB)

  const int t = threadIdx.x;
  const int w = t >> 6, lane = t & 63;
  const int quad = lane >> 4, l16 = lane & 15;
  const int wm2 = w >> 2, wn4 = w & 3;   // 2M x 4N wave grid
  const int m0 = blockIdx.x * 32;

  // ---- stage sampled -> RA (rotated, 2 glds16/thread) --------------------
#pragma unroll
  for (int q = 0; q < 2; ++q) {
    const int g = q * 512 + t;
    const int row = g >> 5, p = g & 31;
    const int cl = (p & ~7) | ((p + row) & 7);
    glds16(sampled + (size_t)(m0 + row) * 256 + cl * 8,
           RA + (q * 512 + w * 64) * 8);
  }
  __syncthreads();

  // ---- wp GEMM: acc[4], K=256 (32 chunks), no barriers ------------------
  {
    f32x4 accp[4];
#pragma unroll
    for (int j = 0; j < 4; j++) accp[j] = (f32x4){0.f, 0.f, 0.f, 0.f};
#pragma unroll
    for (int kk = 0; kk < 8; ++kk) {
      const int c = kk * 4 + quad;
      const int r = wm2 * 16 + l16;
      const int pos = (c & ~7) | ((c - r) & 7);
      const short8 afr = *(const short8*)(RA + r * 256 + pos * 8);
      short8 bfr[4];
#pragma unroll
      for (int j = 0; j < 4; ++j) {
        const int n1 = wn4 * 4 + j;
        bfr[j] = *(const short8*)(wtp + ((size_t)n1 * 32 + c) * 128 + l16 * 8);
      }
#pragma unroll
      for (int j = 0; j < 4; ++j) accp[j] = mfma16(bfr[j], afr, accp[j]);
    }
    // stage wp acc into Q (XOR-swz: col ^ ((row&7)<<2))
#pragma unroll
    for (int j = 0; j < 4; ++j) {
      const int r = wm2 * 16 + l16;
      const int c = wn4 * 64 + j * 16 + quad * 4;
      *(f32x4*)&Q[r * 256 + (c ^ ((r & 7) << 2))] = accp[j];
    }
  }
  __syncthreads();   // Q (wp acc) ready; RA (sampled) reads done

  // ---- LN2: wave w owns rows {w, 8+w, 16+w, 24+w}; qbuf in-place in Q ----
  // query/qnb read directly from global (2nd resident block hides latency).
  {
    const float4 bbp  = *(const float4*)(bp + lane * 4);
    const float4 gv   = *(const float4*)(g2 + lane * 4);
    const float4 bb2  = *(const float4*)(b2v + lane * 4);
#pragma unroll
    for (int rep = 0; rep < 4; ++rep) {
      const int row = rep * 8 + w;
      const int gm = m0 + row;
      const int cs = (lane * 4) ^ ((row & 7) << 2);
      const float4 a  = *(const float4*)&Q[row * 256 + cs];
      const float4 qv = *(const float4*)(query + (size_t)gm * 256 + lane * 4);
      const s16x4 qn  = *(const s16x4*)(qnb + (size_t)gm * 256 + lane * 4);
      float v0 = a.x + bbp.x + b2f(qn.x) + qv.x;
      float v1 = a.y + bbp.y + b2f(qn.y) + qv.y;
      float v2 = a.z + bbp.z + b2f(qn.z) + qv.z;
      float v3 = a.w + bbp.w + b2f(qn.w) + qv.w;
      float s = v0 + v1 + v2 + v3;
#pragma unroll
      for (int o = 32; o; o >>= 1) s += __shfl_xor(s, o);
      const float mean = s * (1.f / 256.f);
      const float d0 = v0 - mean, d1 = v1 - mean, d2 = v2 - mean, d3 = v3 - mean;
      float ss = d0 * d0 + d1 * d1 + d2 * d2 + d3 * d3;
#pragma unroll
      for (int o = 32; o; o >>= 1) ss += __shfl_xor(ss, o);
      const float inv = rsqrtf(ss * (1.f / 256.f) + 1e-5f);
      *(f32x4*)&Q[row * 256 + cs] = (f32x4){v0, v1, v2, v3};  // qbuf
      const int col = lane * 4;
      const int c = col >> 3;
      const int pos = (c & ~7) | ((c - row) & 7);
      s16x4 o2;
      o2.x = f2b(d0 * inv * gv.x + bb2.x);
      o2.y = f2b(d1 * inv * gv.y + bb2.y);
      o2.z = f2b(d2 * inv * gv.z + bb2.z);
      o2.w = f2b(d3 * inv * gv.w + bb2.w);
      *(s16x4*)(RA + row * 256 + pos * 8 + (col & 7)) = o2;
    }
  }
  __syncthreads();   // RA = q2 ready

  // ---- MLP in four 256-col quarters of H ---------------------------------
  f32x4 acc2[4];
#pragma unroll
  for (int j = 0; j < 4; j++) acc2[j] = (f32x4){0.f, 0.f, 0.f, 0.f};

  for (int q = 0; q < 4; ++q) {
    if (q) __syncthreads();            // prior quarter's H reads done
    // phase-1: H-quarter = gelu(q2 @ Wf1[:, q*256:+256] + b1)
    f32x4 acc1[4];
#pragma unroll
    for (int j = 0; j < 4; j++) acc1[j] = (f32x4){0.f, 0.f, 0.f, 0.f};
#pragma unroll
    for (int kk = 0; kk < 8; ++kk) {
      const int cg = kk * 4 + quad;
      const int r = wm2 * 16 + l16;
      const int pos = (cg & ~7) | ((cg - r) & 7);
      const short8 afr = *(const short8*)(RA + r * 256 + pos * 8);
      short8 bfr[4];
#pragma unroll
      for (int j = 0; j < 4; ++j) {
        const int n1 = q * 16 + wn4 * 4 + j;
        bfr[j] = *(const short8*)(wf1 + ((size_t)n1 * 32 + cg) * 128 + l16 * 8);
      }
#pragma unroll
      for (int j = 0; j < 4; ++j) acc1[j] = mfma16(bfr[j], afr, acc1[j]);
    }
    // bias + gelu -> bf16 -> H-quarter (rotated)
#pragma unroll
    for (int j = 0; j < 4; ++j) {
      const int coll = wn4 * 64 + j * 16 + quad * 4;   // local col [0,256)
      const float4 bb = *(const float4*)(b1v + q * 256 + coll);
      const int c = coll >> 3;
      const int r = wm2 * 16 + l16;
      const int pos = (c & ~7) | ((c - r) & 7);
      s16x4 o;
      o.x = f2b(gelu1(acc1[j].x + bb.x));
      o.y = f2b(gelu1(acc1[j].y + bb.y));
      o.z = f2b(gelu1(acc1[j].z + bb.z));
      o.w = f2b(gelu1(acc1[j].w + bb.w));
      *(s16x4*)(H + r * 256 + pos * 8 + (coll & 7)) = o;
    }
    __syncthreads();                   // H-quarter complete

    // phase-2: acc2 += H-quarter @ Wf2[q*256:+256, :]
#pragma unroll 4
    for (int kk = 0; kk < 8; ++kk) {
      const int cl = kk * 4 + quad;    // local chunk [0,32)
      const int r = wm2 * 16 + l16;
      const int pos = (cl & ~7) | ((cl - r) & 7);
      const short8 afr = *(const short8*)(H + r * 256 + pos * 8);
      short8 bfr[4];
#pragma unroll
      for (int j = 0; j < 4; ++j) {
        const int n1 = wn4 * 4 + j;
        bfr[j] = *(const short8*)(wf2 + ((size_t)n1 * 128 + q * 32 + cl) * 128 + l16 * 8);
      }
#pragma unroll
      for (int j = 0; j < 4; ++j) acc2[j] = mfma16(bfr[j], afr, acc2[j]);
    }
  }

  // ---- final add IN PLACE into Q (fragment-owned, race-free) -------------
  {
#pragma unroll
    for (int j = 0; j < 4; ++j) {
      const int r = wm2 * 16 + l16;
      const int c = wn4 * 64 + j * 16 + quad * 4;
      const int cs = c ^ ((r & 7) << 2);
      const float4 bb = *(const float4*)(bf2v + c);
      const float4 qb = *(const float4*)&Q[r * 256 + cs];
      *(f32x4*)&Q[r * 256 + cs] =
          (f32x4){qb.x + acc2[j].x + bb.x, qb.y + acc2[j].y + bb.y,
                  qb.z + acc2[j].z + bb.z, qb.w + acc2[j].w + bb.w};
    }
  }
  __syncthreads();   // all in-place adds visible

  // ---- coalesced store of Q -> out ---------------------------------------
#pragma unroll
  for (int rep = 0; rep < 4; ++rep) {
    const int row = rep * 8 + w;
    const int gm = m0 + row;
    const int cs = (lane * 4) ^ ((row & 7) << 2);
    const float4 v = *(const float4*)&Q[row * 256 + cs];
    *(float4*)(outp + (size_t)gm * 256 + lane * 4) = v;
  }
}

// ---------------------------------------------------------------------------
// prep_all: merged wconvert (1792 blocks) + vconvert (3169) + LN1 (4096).
// Wp/Wf1/Wf2 packed FRAGMENT-MAJOR for direct-global B loads.
// ---------------------------------------------------------------------------
__global__ __launch_bounds__(256) void prep_all(
    const float* __restrict__ Wo, const float* __restrict__ Wa,
    const float* __restrict__ Wv, const float* __restrict__ Wp,
    const float* __restrict__ Wf1, const float* __restrict__ Wf2,
    short* __restrict__ t_oa, short* __restrict__ t_v, short* __restrict__ t_p,
    short* __restrict__ t_f1, short* __restrict__ t_f2,
    const float* __restrict__ value, short* __restrict__ valbf,
    const float* __restrict__ query, const float* __restrict__ query_pos,
    const float* __restrict__ g1, const float* __restrict__ b1,
    short* __restrict__ qnb, short* __restrict__ qa)
{
  __shared__ float tile[32][33];
  const int t = threadIdx.x;
  const int blk = blockIdx.x;

  if (blk < 1792) {
    const int bxa = blk & 255, bya = blk >> 8;
    int K, N, noff; const float* src; short* dst;
    switch (bya) {
      case 0: src = Wo;      dst = t_oa; K = 256;  N = 192;  noff = 0;   break;
      case 1: src = Wa;      dst = t_oa; K = 256;  N = 96;   noff = 192; break;
      case 2: src = nullptr; dst = t_oa; K = 256;  N = 96;   noff = 288; break;
      case 3: src = Wv;      dst = t_v;  K = 256;  N = 256;  noff = 0;   break;
      case 4: src = Wp;      dst = t_p;  K = 256;  N = 256;  noff = 0;   break;
      case 5: src = Wf1;     dst = t_f1; K = 256;  N = 1024; noff = 0;   break;
      default: src = Wf2;    dst = t_f2; K = 1024; N = 256;  noff = 0;   break;
    }
    const bool fragpack = (bya >= 4);
    const int tilesK = K >> 5;
    const int nt = tilesK * (N >> 5);
    if (bxa >= nt) return;
    const int tk = bxa % tilesK, tn = bxa / tilesK;
    const int k0 = tk * 32, n0 = tn * 32;
    const int r = t >> 3, c4 = (t & 7) * 4;
    float4 v = make_float4(0.f, 0.f, 0.f, 0.f);
    if (src) v = *(const float4*)(src + (size_t)(k0 + r) * N + n0 + c4);
    tile[r][c4] = v.x; tile[r][c4 + 1] = v.y; tile[r][c4 + 2] = v.z; tile[r][c4 + 3] = v.w;
    __syncthreads();
    const int nn = t >> 3, kc = (t & 7) * 4;
    s16x4 o;
    o.x = f2b(tile[kc][nn]); o.y = f2b(tile[kc + 1][nn]);
    o.z = f2b(tile[kc + 2][nn]); o.w = f2b(tile[kc + 3][nn]);
    if (fragpack) {
      const int n = n0 + nn, k = k0 + kc;
      *(s16x4*)(dst + ((size_t)(n >> 4) * (K >> 3) + (k >> 3)) * 128 +
                (n & 15) * 8 + (k & 7)) = o;
    } else {
      *(s16x4*)(dst + (size_t)(noff + n0 + nn) * K + k0 + kc) = o;
    }
  } else if (blk < 1792 + 3169) {
    const int i = ((blk - 1792) * 256 + t) * 4;
    if (i >= 12672 * 256) return;
    s16x4 o = (s16x4){0, 0, 0, 0};
    if (i < 12600 * 256) {
      float4 v = *(const float4*)(value + i);
      o.x = f2b(v.x); o.y = f2b(v.y); o.z = f2b(v.z); o.w = f2b(v.w);
    }
    *(s16x4*)(valbf + i) = o;
  } else {
    const int row  = (blk - 4961) * 4 + (t >> 6);
    const int lane = t & 63;
    const float4 v = ((const float4*)(query + (size_t)row * 256))[lane];
    float s = v.x + v.y + v.z + v.w;
#pragma unroll
    for (int o = 32; o; o >>= 1) s += __shfl_xor(s, o);
    const float mean = s * (1.f / 256.f);
    const float dx = v.x - mean, dy = v.y - mean, dz = v.z - mean, dw = v.w - mean;
    float s2 = dx * dx + dy * dy + dz * dz + dw * dw;
#pragma unroll
    for (int o = 32; o; o >>= 1) s2 += __shfl_xor(s2, o);
    const float inv = rsqrtf(s2 * (1.f / 256.f) + 1e-5f);
    const float4 gv = ((const float4*)g1)[lane];
    const float4 bv = ((const float4*)b1)[lane];
    const float4 o1 = make_float4(dx * inv * gv.x + bv.x, dy * inv * gv.y + bv.y,
                                  dz * inv * gv.z + bv.z, dw * inv * gv.w + bv.w);
    s16x4 ob; ob.x = f2b(o1.x); ob.y = f2b(o1.y); ob.z = f2b(o1.z); ob.w = f2b(o1.w);
    ((s16x4*)(qnb + (size_t)row * 256))[lane] = ob;
    const float4 pv = ((const float4*)(query_pos + (size_t)row * 256))[lane];
    s16x4 op;
    op.x = f2b(o1.x + pv.x); op.y = f2b(o1.y + pv.y);
    op.z = f2b(o1.z + pv.z); op.w = f2b(o1.w + pv.w);
    ((s16x4*)(qa + (size_t)row * 256))[lane] = op;
  }
}

// ---------------------------------------------------------------------------
// deform_fused: block = 8 rows. Phase 1 (64 threads): softmax + bilinear
// setup -> LDS tables (oa bf16). Phase 2 (256 threads): gather+FMA.
// ---------------------------------------------------------------------------
__global__ __launch_bounds__(256) void deform_fused(
    const short* __restrict__ vproj, const short* __restrict__ oa,
    const float* __restrict__ refp, short* __restrict__ out)
{
  __shared__ int4 sIdx[768];
  __shared__ s16x4 sW[768];
  const int t = threadIdx.x;

  if (t < 64) {
    const int row = blockIdx.x * 8 + (t >> 3), h = t & 7;
    const short* oarow = oa + (size_t)row * 288;
    float off[24];
    {
      const short8* op = (const short8*)(oarow + h * 24);  // 48 B, 16B-aligned
      b8f(op[0], off); b8f(op[1], off + 8); b8f(op[2], off + 16);
    }
    float lg[12];
    {
      const s16x4* ap = (const s16x4*)(oarow + 192 + h * 12);  // 8B-aligned
#pragma unroll
      for (int i = 0; i < 3; i++) {
        const s16x4 v = ap[i];
        lg[i * 4] = b2f(v.x); lg[i * 4 + 1] = b2f(v.y);
        lg[i * 4 + 2] = b2f(v.z); lg[i * 4 + 3] = b2f(v.w);
      }
    }
    const float* rp = refp + (size_t)row * 6;
    const float Rx[3] = {rp[0], rp[2], rp[4]}, Ry[3] = {rp[1], rp[3], rp[5]};
    float mx = lg[0];
#pragma unroll
    for (int i = 1; i < 12; i++) mx = fmaxf(mx, lg[i]);
    float sum = 0.f;
#pragma unroll
    for (int i = 0; i < 12; i++) { lg[i] = __expf(lg[i] - mx); sum += lg[i]; }
    const float inv = 1.f / sum;
    const int b = row >> 13;
    const int Hs[3] = {60, 30, 15}, Ws[3] = {80, 40, 20}, St[3] = {0, 4800, 6000};
#pragma unroll
    for (int p = 0; p < 12; p++) {
      const int l = p >> 2;
      const int W = Ws[l], H = Hs[l];
      const float gx = Rx[l] * W + off[p * 2]     - 0.5f;
      const float gy = Ry[l] * H + off[p * 2 + 1] - 0.5f;
      const float x0f = floorf(gx), y0f = floorf(gy);
      const float wx = gx - x0f, wy = gy - y0f;
      const int x0 = (int)x0f, y0 = (int)y0f;
      const float aw = lg[p] * inv;
      float cw[4] = {(1.f - wx) * (1.f - wy), wx * (1.f - wy),
                     (1.f - wx) * wy, wx * wy};
      const int base = b * 6300 + St[l];
      int ci[4];
#pragma unroll
      for (int k = 0; k < 4; k++) {
        const int xx = x0 + (k & 1), yy = y0 + (k >> 1);
        const bool valid = (xx >= 0) & (xx < W) & (yy >= 0) & (yy < H);
        const int xc = min(max(xx, 0), W - 1);
        const int yc = min(max(yy, 0), H - 1);
        ci[k] = ((base + yc * W + xc) << 8) + h * 32;
        cw[k] = valid ? cw[k] * aw : 0.f;
      }
      sIdx[t * 12 + p] = make_int4(ci[0], ci[1], ci[2], ci[3]);
      s16x4 wv; wv.x = f2b(cw[0]); wv.y = f2b(cw[1]); wv.z = f2b(cw[2]); wv.w = f2b(cw[3]);
      sW[t * 12 + p] = wv;
    }
  }
  __syncthreads();

  const int lu = t >> 2, c4 = (t & 3) * 8;
  float acc[8];
#pragma unroll
  for (int i = 0; i < 8; i++) acc[i] = 0.f;
#pragma unroll 2
  for (int p = 0; p < 12; p++) {
    const int4 idx = sIdx[lu * 12 + p];
    const s16x4 wb = sW[lu * 12 + p];
    const float w0 = b2f(wb.x), w1 = b2f(wb.y), w2 = b2f(wb.z), w3 = b2f(wb.w);
    const short8 v0 = *(const short8*)(vproj + idx.x + c4);
    const short8 v1 = *(const short8*)(vproj + idx.y + c4);
    const short8 v2 = *(const short8*)(vproj + idx.z + c4);
    const short8 v3 = *(const short8*)(vproj + idx.w + c4);
    float f0[8], f1[8], f2[8], f3[8];
    b8f(v0, f0); b8f(v1, f1); b8f(v2, f2); b8f(v3, f3);
#pragma unroll
    for (int j = 0; j < 8; j++)
      acc[j] += w0 * f0[j] + w1 * f1[j] + w2 * f2[j] + w3 * f3[j];
  }
  short8 o;
#pragma unroll
  for (int j = 0; j < 8; j++) o[j] = f2b(acc[j]);
  *(short8*)(out + (size_t)(blockIdx.x * 256 + t) * 8) = o;
}

// ---------------------------------------------------------------------------
// Launch
// ---------------------------------------------------------------------------
extern "C" void kernel_launch(void* const* d_in, const int* in_sizes, int n_in,
                              void* d_out, int out_size, void* d_ws, size_t ws_size,
                              hipStream_t stream)
{
  const float* query     = (const float*)d_in[0];
  const float* value     = (const float*)d_in[1];
  const float* query_pos = (const float*)d_in[2];
  const float* ref_pts   = (const float*)d_in[3];
  const float* g1  = (const float*)d_in[6];
  const float* b1  = (const float*)d_in[7];
  const float* Wo  = (const float*)d_in[8];
  const float* bo  = (const float*)d_in[9];
  const float* Wa  = (const float*)d_in[10];
  const float* ba  = (const float*)d_in[11];
  const float* Wv  = (const float*)d_in[12];
  const float* bv  = (const float*)d_in[13];
  const float* Wp  = (const float*)d_in[14];
  const float* bp  = (const float*)d_in[15];
  const float* g2  = (const float*)d_in[16];
  const float* b2  = (const float*)d_in[17];
  const float* Wf1 = (const float*)d_in[18];
  const float* bf1 = (const float*)d_in[19];
  const float* Wf2 = (const float*)d_in[20];
  const float* bf2 = (const float*)d_in[21];

  char* ws = (char*)d_ws;
  short* wt_oa   = (short*)(ws + 0);          // 384x256 bf16
  short* wt_v    = (short*)(ws + 196608);
  short* wt_p    = (short*)(ws + 327680);     // frag-major packed
  short* wt_f1   = (short*)(ws + 458752);     // frag-major packed
  short* wt_f2   = (short*)(ws + 983040);     // frag-major packed
  short* qnb     = (short*)(ws + 1507328);    // 16384x256 bf16 (LN1, no pos)
  short* qa      = (short*)(ws + 18284544);   // 16384x256 bf16
  short* oabuf   = (short*)(ws + 26673152);   // 16384x288 bf16 (9.4 MB)
  short* vproj   = (short*)(ws + 45547520);   // 12600x256 bf16
  short* sampled = (short*)(ws + 51998720);   // 16384x256 bf16
  short* valbf   = (short*)(ws + 77164544);   // 12672x256 bf16
  float* outp = (float*)d_out;

  // 1. merged: weight convert/pack + value convert + LN1
  prep_all<<<9057, 256, 0, stream>>>(Wo, Wa, Wv, Wp, Wf1, Wf2,
                                     wt_oa, wt_v, wt_p, wt_f1, wt_f2,
                                     value, valbf, query, query_pos,
                                     g1, b1, qnb, qa);
  // 2. merged GEMMs: oa (768 blocks, bf16 out) + vproj (394 blocks)
  gemm_oa_v<<<1162, 256, 0, stream>>>(qa, wt_oa, bo, ba, oabuf,
                                      valbf, wt_v, bv, vproj);
  // 3. fused prep+gather -> sampled bf16
  deform_fused<<<2048, 256, 0, stream>>>(vproj, oabuf, ref_pts, sampled);
  // 4. merged Wp-GEMM + LN2 + MLP (64 KB LDS, 2 blocks/CU, zero spill)
  wp_mlp<<<512, 512, 0, stream>>>(sampled, wt_p, bp, qnb, query, g2, b2,
                                  wt_f1, bf1, wt_f2, bf2, outp);
}

// Round 9
// 206.941 us; speedup vs baseline: 1.2024x; 1.0613x over previous
//
#include <hip/hip_runtime.h>
#include <math.h>

// ---------------------------------------------------------------------------
// Deformable transformer layer, MI355X round-24:
//  - prep_all / gemm_oa_v / deform_fused kept (rounds 10-23).
//  - wp_mlp: r21 x r23 hybrid. 64-row block (grid 256: weights read ONCE per
//    CU -> half of r23's L2 weight traffic) + r23's small-acc quarter
//    structure (acc1/acc2 = 2x2 each -> no spill; r21 spilled 7 MB).
//    LDS 128 KB: Q[64][256]f32 XOR-swz | H quarter [64][256]bf16 | RA 32KB.
//    16 waves/CU. LN2 reads query/qnb direct (exposure ~0.4us, negligible).
//  4 dispatches.
// B=2, Nq=8192, C=256, HEADS=8, dh=32, LEVELS=3, POINTS=4, MLP=4
// ---------------------------------------------------------------------------

typedef short short8 __attribute__((ext_vector_type(8)));
typedef short s16x4 __attribute__((ext_vector_type(4)));
typedef __bf16 bf16x8 __attribute__((ext_vector_type(8)));
typedef float f32x4 __attribute__((ext_vector_type(4)));

#if defined(__has_attribute)
#if __has_attribute(amdgpu_num_vgpr)
#define WPMLP_REGS __attribute__((amdgpu_num_vgpr(128)))
#else
#define WPMLP_REGS
#endif
#else
#define WPMLP_REGS
#endif

__device__ __forceinline__ short f2b(float f) {
  unsigned u = __builtin_bit_cast(unsigned, f);
  u += 0x7fffu + ((u >> 16) & 1u);   // RNE to bf16
  return (short)(u >> 16);
}
__device__ __forceinline__ float b2f(short s) {
  unsigned u = ((unsigned)(unsigned short)s) << 16;
  return __builtin_bit_cast(float, u);
}
__device__ __forceinline__ void b8f(short8 s, float* f) {
  const uint4 u = __builtin_bit_cast(uint4, s);
  f[0] = __builtin_bit_cast(float, u.x << 16);
  f[1] = __builtin_bit_cast(float, u.x & 0xffff0000u);
  f[2] = __builtin_bit_cast(float, u.y << 16);
  f[3] = __builtin_bit_cast(float, u.y & 0xffff0000u);
  f[4] = __builtin_bit_cast(float, u.z << 16);
  f[5] = __builtin_bit_cast(float, u.z & 0xffff0000u);
  f[6] = __builtin_bit_cast(float, u.w << 16);
  f[7] = __builtin_bit_cast(float, u.w & 0xffff0000u);
}

__device__ __forceinline__ f32x4 mfma16(short8 a, short8 b, f32x4 c) {
  return __builtin_amdgcn_mfma_f32_16x16x32_bf16(
      __builtin_bit_cast(bf16x8, a), __builtin_bit_cast(bf16x8, b), c, 0, 0, 0);
}

typedef __attribute__((address_space(3))) unsigned int lds_u32;
typedef const __attribute__((address_space(1))) unsigned int glb_u32;
__device__ __forceinline__ void glds16(const void* g, void* l) {
  __builtin_amdgcn_global_load_lds((glb_u32*)g, (lds_u32*)l, 16, 0, 0);
}

__device__ __forceinline__ float gelu1(float v) {
  return 0.5f * v * (1.f + erff(v * 0.70710678118654752f));
}

// ---------------------------------------------------------------------------
// GEMM core 64x128 tile, BK=64, 24 KB LDS (used by oa/v merged GEMM).
// EPI: 4=oa (bias split 192/96, bf16 out) | 5=bf16+bias
// ---------------------------------------------------------------------------
template <int EPI>
__device__ __forceinline__ void gemm64_core(
    int bx, int by,
    const short* __restrict__ A, const short* __restrict__ Bt,
    const float* __restrict__ bias, const float* __restrict__ bias2,
    void* __restrict__ Cout, int M, int Nreal, int ldc, int K, char* smem)
{
  short* sA = (short*)smem;       // [64][64] shorts (8 KB)
  short* sB = sA + 4096;          // [128][64] shorts (16 KB)
  float* sf = (float*)smem;       // epilogue staging [32][132]

  const int t = threadIdx.x;
  const int wave = t >> 6, lane = t & 63;
  const int quad = lane >> 4, l16 = lane & 15;
  const int wm = (wave & 1) * 32, wn = (wave >> 1) * 64;
  const int m0 = by * 64, n0 = bx * 128;

  f32x4 acc[2][4];
#pragma unroll
  for (int i = 0; i < 2; i++)
#pragma unroll
    for (int j = 0; j < 4; j++) acc[i][j] = (f32x4){0.f, 0.f, 0.f, 0.f};

  const int srow = lane >> 3, pos = lane & 7;
  const int chunk = (pos + srow) & 7;
  const short* gA = A + (size_t)(m0 + wave * 16 + srow) * K + chunk * 8;
  const short* gB = Bt + (size_t)(n0 + wave * 32 + srow) * K + chunk * 8;

  const int nk = K >> 6;
  for (int kt = 0; kt < nk; ++kt) {
    if (kt) __syncthreads();
    const int ko = kt * 64;
#pragma unroll
    for (int g = 0; g < 2; ++g)
      glds16(gA + ko + (size_t)(g * 8) * K, sA + (wave * 16 + g * 8) * 64);
#pragma unroll
    for (int g = 0; g < 4; ++g)
      glds16(gB + ko + (size_t)(g * 8) * K, sB + (wave * 32 + g * 8) * 64);
    __syncthreads();
#pragma unroll
    for (int kk = 0; kk < 2; ++kk) {
      short8 af[2], bf[4];
      const int c = kk * 4 + quad;
#pragma unroll
      for (int i = 0; i < 2; i++) {
        const int lrA = wm + i * 16 + l16;
        af[i] = *(const short8*)&sA[lrA * 64 + ((c - lrA) & 7) * 8];
      }
#pragma unroll
      for (int j = 0; j < 4; j++) {
        const int lrB = wn + j * 16 + l16;
        bf[j] = *(const short8*)&sB[lrB * 64 + ((c - lrB) & 7) * 8];
      }
#pragma unroll
      for (int i = 0; i < 2; i++)
#pragma unroll
        for (int j = 0; j < 4; j++) acc[i][j] = mfma16(bf[j], af[i], acc[i][j]);
    }
  }
  __syncthreads();

  // Epilogue: 2 bands of 32 rows x 128 cols, coalesced full-line stores.
#pragma unroll
  for (int b = 0; b < 2; ++b) {
    if (wm == b * 32) {
#pragma unroll
      for (int i = 0; i < 2; ++i) {
        const int rr = i * 16 + l16;
#pragma unroll
        for (int j = 0; j < 4; ++j)
          *(f32x4*)&sf[rr * 132 + wn + quad * 4 + j * 16] = acc[i][j];
      }
    }
    __syncthreads();
#pragma unroll
    for (int r2 = 0; r2 < 4; ++r2) {
      const int fidx = r2 * 1024 + t * 4;
      const int row = fidx >> 7, col = fidx & 127;
      const int gm = m0 + b * 32 + row;
      const int cc = n0 + col;
      if (gm < M && cc < Nreal) {
        const float4 v = *(const float4*)&sf[row * 132 + col];
        float4 bb;
        if (EPI == 4) bb = (cc < 192) ? *(const float4*)(bias + cc)
                                      : *(const float4*)(bias2 + cc - 192);
        else bb = *(const float4*)(bias + cc);
        float v0 = v.x + bb.x, v1 = v.y + bb.y, v2 = v.z + bb.z, v3 = v.w + bb.w;
        s16x4 o; o.x = f2b(v0); o.y = f2b(v1); o.z = f2b(v2); o.w = f2b(v3);
        *(s16x4*)((short*)Cout + (size_t)gm * ldc + cc) = o;
      }
    }
    __syncthreads();
  }
}

// Merged: blocks [0,768) -> oa GEMM (EPI4, bf16 out), [768,1162) -> v (EPI5)
__global__ __launch_bounds__(256) void gemm_oa_v(
    const short* __restrict__ qa, const short* __restrict__ wt_oa,
    const float* __restrict__ bo, const float* __restrict__ ba,
    short* __restrict__ oabuf,
    const short* __restrict__ valbf, const short* __restrict__ wt_v,
    const float* __restrict__ bv, short* __restrict__ vproj)
{
  __shared__ __align__(16) char smem[24576];
  const int idx = blockIdx.x;
  if (idx < 768) {
    gemm64_core<4>(idx % 3, idx / 3, qa, wt_oa, bo, ba,
                   oabuf, 16384, 288, 288, 256, smem);
  } else {
    const int r = idx - 768;
    gemm64_core<5>(r % 2, r / 2, valbf, wt_v, bv, nullptr,
                   vproj, 12600, 256, 256, 256, smem);
  }
}

// ---------------------------------------------------------------------------
// wp_mlp: per 64-row block (grid 256, 1024 threads, 128 KB LDS, 16 waves/CU):
//   Q  = sampled@Wp (XOR-swz) -> qbuf in-place -> final out in-place
//   RA = sampled (rotated) -> q2 (rotated)
//   H  = one 256-col quarter of hidden (rotated), 4 quarters total
//   out = Q (qbuf + H@Wf2 + bf2, accumulated in place)
// Weights read ONCE per block (grid 256 = 1/CU). acc1/acc2 2x2 -> no spill.
// ---------------------------------------------------------------------------
__global__ __launch_bounds__(1024) WPMLP_REGS void wp_mlp(
    const short* __restrict__ sampled,  // [16384][256] bf16
    const short* __restrict__ wtp,      // frag-major K=256 N=256
    const float* __restrict__ bp,
    const short* __restrict__ qnb,      // [16384][256] bf16
    const float* __restrict__ query,    // [16384][256] f32
    const float* __restrict__ g2, const float* __restrict__ b2v,
    const short* __restrict__ wf1,      // frag-major K=256 N=1024
    const float* __restrict__ b1v,
    const short* __restrict__ wf2,      // frag-major K=1024 N=256
    const float* __restrict__ bf2v,
    float* __restrict__ outp)           // [16384][256] f32
{
  __shared__ __align__(16) char smem[131072];
  float* Q  = (float*)smem;             // [64][256] f32, XOR-swz (64 KB)
  short* H  = (short*)(smem + 65536);   // [64][256] bf16 quarter (32 KB)
  short* RA = (short*)(smem + 98304);   // [64][256] bf16 rotated (32 KB)

  const int t = threadIdx.x;
  const int w = t >> 6, lane = t & 63;
  const int quad = lane >> 4, l16 = lane & 15;
  const int wm2 = w >> 3, wn8 = w & 7;   // 2M x 8N wave grid
  const int m0 = blockIdx.x * 64;

  // ---- stage sampled -> RA (rotated, 2 glds16/thread) --------------------
#pragma unroll
  for (int qq = 0; qq < 2; ++qq) {
    const int g = qq * 1024 + t;
    const int row = g >> 5, p = g & 31;
    const int cl = (p & ~7) | ((p + row) & 7);
    glds16(sampled + (size_t)(m0 + row) * 256 + cl * 8,
           RA + (qq * 1024 + w * 64) * 8);
  }
  __syncthreads();

  // ---- wp GEMM: acc[2][2], K=256 (32 chunks), no barriers ---------------
  {
    f32x4 accp[2][2];
#pragma unroll
    for (int i = 0; i < 2; i++)
#pragma unroll
      for (int j = 0; j < 2; j++) accp[i][j] = (f32x4){0.f, 0.f, 0.f, 0.f};
#pragma unroll
    for (int kk = 0; kk < 8; ++kk) {
      const int c = kk * 4 + quad;
      short8 afr[2], bfr[2];
#pragma unroll
      for (int i = 0; i < 2; ++i) {
        const int r = wm2 * 32 + i * 16 + l16;
        const int pos = (c & ~7) | ((c - r) & 7);
        afr[i] = *(const short8*)(RA + r * 256 + pos * 8);
      }
#pragma unroll
      for (int j = 0; j < 2; ++j) {
        const int n1 = wn8 * 2 + j;
        bfr[j] = *(const short8*)(wtp + ((size_t)n1 * 32 + c) * 128 + l16 * 8);
      }
#pragma unroll
      for (int i = 0; i < 2; ++i)
#pragma unroll
        for (int j = 0; j < 2; ++j) accp[i][j] = mfma16(bfr[j], afr[i], accp[i][j]);
    }
    // stage wp acc into Q (XOR-swz: col ^ ((row&7)<<2))
#pragma unroll
    for (int i = 0; i < 2; ++i)
#pragma unroll
      for (int j = 0; j < 2; ++j) {
        const int r = wm2 * 32 + i * 16 + l16;
        const int cc = wn8 * 32 + j * 16 + quad * 4;
        *(f32x4*)&Q[r * 256 + (cc ^ ((r & 7) << 2))] = accp[i][j];
      }
  }
  __syncthreads();   // Q (wp acc) ready; RA (sampled) reads done

  // ---- LN2: wave w owns rows {w, 16+w, 32+w, 48+w}; qbuf in-place in Q ---
  // query/qnb read directly from global (exposure ~0.4us/block-round).
  {
    const float4 bbp  = *(const float4*)(bp + lane * 4);
    const float4 gv   = *(const float4*)(g2 + lane * 4);
    const float4 bb2  = *(const float4*)(b2v + lane * 4);
#pragma unroll
    for (int rep = 0; rep < 4; ++rep) {
      const int row = rep * 16 + w;
      const int gm = m0 + row;
      const int cs = (lane * 4) ^ ((row & 7) << 2);
      const float4 a  = *(const float4*)&Q[row * 256 + cs];
      const float4 qv = *(const float4*)(query + (size_t)gm * 256 + lane * 4);
      const s16x4 qn  = *(const s16x4*)(qnb + (size_t)gm * 256 + lane * 4);
      float v0 = a.x + bbp.x + b2f(qn.x) + qv.x;
      float v1 = a.y + bbp.y + b2f(qn.y) + qv.y;
      float v2 = a.z + bbp.z + b2f(qn.z) + qv.z;
      float v3 = a.w + bbp.w + b2f(qn.w) + qv.w;
      float s = v0 + v1 + v2 + v3;
#pragma unroll
      for (int o = 32; o; o >>= 1) s += __shfl_xor(s, o);
      const float mean = s * (1.f / 256.f);
      const float d0 = v0 - mean, d1 = v1 - mean, d2 = v2 - mean, d3 = v3 - mean;
      float ss = d0 * d0 + d1 * d1 + d2 * d2 + d3 * d3;
#pragma unroll
      for (int o = 32; o; o >>= 1) ss += __shfl_xor(ss, o);
      const float inv = rsqrtf(ss * (1.f / 256.f) + 1e-5f);
      *(f32x4*)&Q[row * 256 + cs] = (f32x4){v0, v1, v2, v3};  // qbuf
      const int col = lane * 4;
      const int c = col >> 3;
      const int pos = (c & ~7) | ((c - row) & 7);
      s16x4 o2;
      o2.x = f2b(d0 * inv * gv.x + bb2.x);
      o2.y = f2b(d1 * inv * gv.y + bb2.y);
      o2.z = f2b(d2 * inv * gv.z + bb2.z);
      o2.w = f2b(d3 * inv * gv.w + bb2.w);
      *(s16x4*)(RA + row * 256 + pos * 8 + (col & 7)) = o2;
    }
  }
  __syncthreads();   // RA = q2 ready

  // ---- MLP in four 256-col quarters of H ---------------------------------
  f32x4 acc2[2][2];
#pragma unroll
  for (int i = 0; i < 2; i++)
#pragma unroll
    for (int j = 0; j < 2; j++) acc2[i][j] = (f32x4){0.f, 0.f, 0.f, 0.f};

  for (int q = 0; q < 4; ++q) {
    if (q) __syncthreads();            // prior quarter's H reads done
    // phase-1: H-quarter = gelu(q2 @ Wf1[:, q*256:+256] + b1)
    f32x4 acc1[2][2];
#pragma unroll
    for (int i = 0; i < 2; i++)
#pragma unroll
      for (int j = 0; j < 2; j++) acc1[i][j] = (f32x4){0.f, 0.f, 0.f, 0.f};
#pragma unroll
    for (int kk = 0; kk < 8; ++kk) {
      const int cg = kk * 4 + quad;
      short8 afr[2], bfr[2];
#pragma unroll
      for (int i = 0; i < 2; ++i) {
        const int r = wm2 * 32 + i * 16 + l16;
        const int pos = (cg & ~7) | ((cg - r) & 7);
        afr[i] = *(const short8*)(RA + r * 256 + pos * 8);
      }
#pragma unroll
      for (int j = 0; j < 2; ++j) {
        const int n1 = q * 16 + wn8 * 2 + j;
        bfr[j] = *(const short8*)(wf1 + ((size_t)n1 * 32 + cg) * 128 + l16 * 8);
      }
#pragma unroll
      for (int i = 0; i < 2; ++i)
#pragma unroll
        for (int j = 0; j < 2; ++j) acc1[i][j] = mfma16(bfr[j], afr[i], acc1[i][j]);
    }
    // bias + gelu -> bf16 -> H-quarter (rotated)
#pragma unroll
    for (int j = 0; j < 2; ++j) {
      const int coll = wn8 * 32 + j * 16 + quad * 4;   // local col [0,256)
      const float4 bb = *(const float4*)(b1v + q * 256 + coll);
      const int c = coll >> 3;
#pragma unroll
      for (int i = 0; i < 2; ++i) {
        const int r = wm2 * 32 + i * 16 + l16;
        const int pos = (c & ~7) | ((c - r) & 7);
        s16x4 o;
        o.x = f2b(gelu1(acc1[i][j].x + bb.x));
        o.y = f2b(gelu1(acc1[i][j].y + bb.y));
        o.z = f2b(gelu1(acc1[i][j].z + bb.z));
        o.w = f2b(gelu1(acc1[i][j].w + bb.w));
        *(s16x4*)(H + r * 256 + pos * 8 + (coll & 7)) = o;
      }
    }
    __syncthreads();                   // H-quarter complete

    // phase-2: acc2 += H-quarter @ Wf2[q*256:+256, :]
#pragma unroll 4
    for (int kk = 0; kk < 8; ++kk) {
      const int cl = kk * 4 + quad;    // local chunk [0,32)
      short8 afr[2], bfr[2];
#pragma unroll
      for (int i = 0; i < 2; ++i) {
        const int r = wm2 * 32 + i * 16 + l16;
        const int pos = (cl & ~7) | ((cl - r) & 7);
        afr[i] = *(const short8*)(H + r * 256 + pos * 8);
      }
#pragma unroll
      for (int j = 0; j < 2; ++j) {
        const int n1 = wn8 * 2 + j;
        bfr[j] = *(const short8*)(wf2 + ((size_t)n1 * 128 + q * 32 + cl) * 128 + l16 * 8);
      }
#pragma unroll
      for (int i = 0; i < 2; ++i)
#pragma unroll
        for (int j = 0; j < 2; ++j) acc2[i][j] = mfma16(bfr[j], afr[i], acc2[i][j]);
    }
  }

  // ---- final add IN PLACE into Q (fragment-owned, race-free) -------------
  {
#pragma unroll
    for (int i = 0; i < 2; ++i)
#pragma unroll
      for (int j = 0; j < 2; ++j) {
        const int r = wm2 * 32 + i * 16 + l16;
        const int cc = wn8 * 32 + j * 16 + quad * 4;
        const int cs = cc ^ ((r & 7) << 2);
        const float4 bb = *(const float4*)(bf2v + cc);
        const float4 qb = *(const float4*)&Q[r * 256 + cs];
        *(f32x4*)&Q[r * 256 + cs] =
            (f32x4){qb.x + acc2[i][j].x + bb.x, qb.y + acc2[i][j].y + bb.y,
                    qb.z + acc2[i][j].z + bb.z, qb.w + acc2[i][j].w + bb.w};
      }
  }
  __syncthreads();   // all in-place adds visible

  // ---- coalesced store of Q -> out ---------------------------------------
#pragma unroll
  for (int rep = 0; rep < 4; ++rep) {
    const int row = rep * 16 + w;
    const int gm = m0 + row;
    const int cs = (lane * 4) ^ ((row & 7) << 2);
    const float4 v = *(const float4*)&Q[row * 256 + cs];
    *(float4*)(outp + (size_t)gm * 256 + lane * 4) = v;
  }
}

// ---------------------------------------------------------------------------
// prep_all: merged wconvert (1792 blocks) + vconvert (3169) + LN1 (4096).
// Wp/Wf1/Wf2 packed FRAGMENT-MAJOR for direct-global B loads.
// ---------------------------------------------------------------------------
__global__ __launch_bounds__(256) void prep_all(
    const float* __restrict__ Wo, const float* __restrict__ Wa,
    const float* __restrict__ Wv, const float* __restrict__ Wp,
    const float* __restrict__ Wf1, const float* __restrict__ Wf2,
    short* __restrict__ t_oa, short* __restrict__ t_v, short* __restrict__ t_p,
    short* __restrict__ t_f1, short* __restrict__ t_f2,
    const float* __restrict__ value, short* __restrict__ valbf,
    const float* __restrict__ query, const float* __restrict__ query_pos,
    const float* __restrict__ g1, const float* __restrict__ b1,
    short* __restrict__ qnb, short* __restrict__ qa)
{
  __shared__ float tile[32][33];
  const int t = threadIdx.x;
  const int blk = blockIdx.x;

  if (blk < 1792) {
    const int bxa = blk & 255, bya = blk >> 8;
    int K, N, noff; const float* src; short* dst;
    switch (bya) {
      case 0: src = Wo;      dst = t_oa; K = 256;  N = 192;  noff = 0;   break;
      case 1: src = Wa;      dst = t_oa; K = 256;  N = 96;   noff = 192; break;
      case 2: src = nullptr; dst = t_oa; K = 256;  N = 96;   noff = 288; break;
      case 3: src = Wv;      dst = t_v;  K = 256;  N = 256;  noff = 0;   break;
      case 4: src = Wp;      dst = t_p;  K = 256;  N = 256;  noff = 0;   break;
      case 5: src = Wf1;     dst = t_f1; K = 256;  N = 1024; noff = 0;   break;
      default: src = Wf2;    dst = t_f2; K = 1024; N = 256;  noff = 0;   break;
    }
    const bool fragpack = (bya >= 4);
    const int tilesK = K >> 5;
    const int nt = tilesK * (N >> 5);
    if (bxa >= nt) return;
    const int tk = bxa % tilesK, tn = bxa / tilesK;
    const int k0 = tk * 32, n0 = tn * 32;
    const int r = t >> 3, c4 = (t & 7) * 4;
    float4 v = make_float4(0.f, 0.f, 0.f, 0.f);
    if (src) v = *(const float4*)(src + (size_t)(k0 + r) * N + n0 + c4);
    tile[r][c4] = v.x; tile[r][c4 + 1] = v.y; tile[r][c4 + 2] = v.z; tile[r][c4 + 3] = v.w;
    __syncthreads();
    const int nn = t >> 3, kc = (t & 7) * 4;
    s16x4 o;
    o.x = f2b(tile[kc][nn]); o.y = f2b(tile[kc + 1][nn]);
    o.z = f2b(tile[kc + 2][nn]); o.w = f2b(tile[kc + 3][nn]);
    if (fragpack) {
      const int n = n0 + nn, k = k0 + kc;
      *(s16x4*)(dst + ((size_t)(n >> 4) * (K >> 3) + (k >> 3)) * 128 +
                (n & 15) * 8 + (k & 7)) = o;
    } else {
      *(s16x4*)(dst + (size_t)(noff + n0 + nn) * K + k0 + kc) = o;
    }
  } else if (blk < 1792 + 3169) {
    const int i = ((blk - 1792) * 256 + t) * 4;
    if (i >= 12672 * 256) return;
    s16x4 o = (s16x4){0, 0, 0, 0};
    if (i < 12600 * 256) {
      float4 v = *(const float4*)(value + i);
      o.x = f2b(v.x); o.y = f2b(v.y); o.z = f2b(v.z); o.w = f2b(v.w);
    }
    *(s16x4*)(valbf + i) = o;
  } else {
    const int row  = (blk - 4961) * 4 + (t >> 6);
    const int lane = t & 63;
    const float4 v = ((const float4*)(query + (size_t)row * 256))[lane];
    float s = v.x + v.y + v.z + v.w;
#pragma unroll
    for (int o = 32; o; o >>= 1) s += __shfl_xor(s, o);
    const float mean = s * (1.f / 256.f);
    const float dx = v.x - mean, dy = v.y - mean, dz = v.z - mean, dw = v.w - mean;
    float s2 = dx * dx + dy * dy + dz * dz + dw * dw;
#pragma unroll
    for (int o = 32; o; o >>= 1) s2 += __shfl_xor(s2, o);
    const float inv = rsqrtf(s2 * (1.f / 256.f) + 1e-5f);
    const float4 gv = ((const float4*)g1)[lane];
    const float4 bv = ((const float4*)b1)[lane];
    const float4 o1 = make_float4(dx * inv * gv.x + bv.x, dy * inv * gv.y + bv.y,
                                  dz * inv * gv.z + bv.z, dw * inv * gv.w + bv.w);
    s16x4 ob; ob.x = f2b(o1.x); ob.y = f2b(o1.y); ob.z = f2b(o1.z); ob.w = f2b(o1.w);
    ((s16x4*)(qnb + (size_t)row * 256))[lane] = ob;
    const float4 pv = ((const float4*)(query_pos + (size_t)row * 256))[lane];
    s16x4 op;
    op.x = f2b(o1.x + pv.x); op.y = f2b(o1.y + pv.y);
    op.z = f2b(o1.z + pv.z); op.w = f2b(o1.w + pv.w);
    ((s16x4*)(qa + (size_t)row * 256))[lane] = op;
  }
}

// ---------------------------------------------------------------------------
// deform_fused: block = 8 rows. Phase 1 (64 threads): softmax + bilinear
// setup -> LDS tables (oa bf16). Phase 2 (256 threads): gather+FMA.
// ---------------------------------------------------------------------------
__global__ __launch_bounds__(256) void deform_fused(
    const short* __restrict__ vproj, const short* __restrict__ oa,
    const float* __restrict__ refp, short* __restrict__ out)
{
  __shared__ int4 sIdx[768];
  __shared__ s16x4 sW[768];
  const int t = threadIdx.x;

  if (t < 64) {
    const int row = blockIdx.x * 8 + (t >> 3), h = t & 7;
    const short* oarow = oa + (size_t)row * 288;
    float off[24];
    {
      const short8* op = (const short8*)(oarow + h * 24);  // 48 B, 16B-aligned
      b8f(op[0], off); b8f(op[1], off + 8); b8f(op[2], off + 16);
    }
    float lg[12];
    {
      const s16x4* ap = (const s16x4*)(oarow + 192 + h * 12);  // 8B-aligned
#pragma unroll
      for (int i = 0; i < 3; i++) {
        const s16x4 v = ap[i];
        lg[i * 4] = b2f(v.x); lg[i * 4 + 1] = b2f(v.y);
        lg[i * 4 + 2] = b2f(v.z); lg[i * 4 + 3] = b2f(v.w);
      }
    }
    const float* rp = refp + (size_t)row * 6;
    const float Rx[3] = {rp[0], rp[2], rp[4]}, Ry[3] = {rp[1], rp[3], rp[5]};
    float mx = lg[0];
#pragma unroll
    for (int i = 1; i < 12; i++) mx = fmaxf(mx, lg[i]);
    float sum = 0.f;
#pragma unroll
    for (int i = 0; i < 12; i++) { lg[i] = __expf(lg[i] - mx); sum += lg[i]; }
    const float inv = 1.f / sum;
    const int b = row >> 13;
    const int Hs[3] = {60, 30, 15}, Ws[3] = {80, 40, 20}, St[3] = {0, 4800, 6000};
#pragma unroll
    for (int p = 0; p < 12; p++) {
      const int l = p >> 2;
      const int W = Ws[l], H = Hs[l];
      const float gx = Rx[l] * W + off[p * 2]     - 0.5f;
      const float gy = Ry[l] * H + off[p * 2 + 1] - 0.5f;
      const float x0f = floorf(gx), y0f = floorf(gy);
      const float wx = gx - x0f, wy = gy - y0f;
      const int x0 = (int)x0f, y0 = (int)y0f;
      const float aw = lg[p] * inv;
      float cw[4] = {(1.f - wx) * (1.f - wy), wx * (1.f - wy),
                     (1.f - wx) * wy, wx * wy};
      const int base = b * 6300 + St[l];
      int ci[4];
#pragma unroll
      for (int k = 0; k < 4; k++) {
        const int xx = x0 + (k & 1), yy = y0 + (k >> 1);
        const bool valid = (xx >= 0) & (xx < W) & (yy >= 0) & (yy < H);
        const int xc = min(max(xx, 0), W - 1);
        const int yc = min(max(yy, 0), H - 1);
        ci[k] = ((base + yc * W + xc) << 8) + h * 32;
        cw[k] = valid ? cw[k] * aw : 0.f;
      }
      sIdx[t * 12 + p] = make_int4(ci[0], ci[1], ci[2], ci[3]);
      s16x4 wv; wv.x = f2b(cw[0]); wv.y = f2b(cw[1]); wv.z = f2b(cw[2]); wv.w = f2b(cw[3]);
      sW[t * 12 + p] = wv;
    }
  }
  __syncthreads();

  const int lu = t >> 2, c4 = (t & 3) * 8;
  float acc[8];
#pragma unroll
  for (int i = 0; i < 8; i++) acc[i] = 0.f;
#pragma unroll 2
  for (int p = 0; p < 12; p++) {
    const int4 idx = sIdx[lu * 12 + p];
    const s16x4 wb = sW[lu * 12 + p];
    const float w0 = b2f(wb.x), w1 = b2f(wb.y), w2 = b2f(wb.z), w3 = b2f(wb.w);
    const short8 v0 = *(const short8*)(vproj + idx.x + c4);
    const short8 v1 = *(const short8*)(vproj + idx.y + c4);
    const short8 v2 = *(const short8*)(vproj + idx.z + c4);
    const short8 v3 = *(const short8*)(vproj + idx.w + c4);
    float f0[8], f1[8], f2[8], f3[8];
    b8f(v0, f0); b8f(v1, f1); b8f(v2, f2); b8f(v3, f3);
#pragma unroll
    for (int j = 0; j < 8; j++)
      acc[j] += w0 * f0[j] + w1 * f1[j] + w2 * f2[j] + w3 * f3[j];
  }
  short8 o;
#pragma unroll
  for (int j = 0; j < 8; j++) o[j] = f2b(acc[j]);
  *(short8*)(out + (size_t)(blockIdx.x * 256 + t) * 8) = o;
}

// ---------------------------------------------------------------------------
// Launch
// ---------------------------------------------------------------------------
extern "C" void kernel_launch(void* const* d_in, const int* in_sizes, int n_in,
                              void* d_out, int out_size, void* d_ws, size_t ws_size,
                              hipStream_t stream)
{
  const float* query     = (const float*)d_in[0];
  const float* value     = (const float*)d_in[1];
  const float* query_pos = (const float*)d_in[2];
  const float* ref_pts   = (const float*)d_in[3];
  const float* g1  = (const float*)d_in[6];
  const float* b1  = (const float*)d_in[7];
  const float* Wo  = (const float*)d_in[8];
  const float* bo  = (const float*)d_in[9];
  const float* Wa  = (const float*)d_in[10];
  const float* ba  = (const float*)d_in[11];
  const float* Wv  = (const float*)d_in[12];
  const float* bv  = (const float*)d_in[13];
  const float* Wp  = (const float*)d_in[14];
  const float* bp  = (const float*)d_in[15];
  const float* g2  = (const float*)d_in[16];
  const float* b2  = (const float*)d_in[17];
  const float* Wf1 = (const float*)d_in[18];
  const float* bf1 = (const float*)d_in[19];
  const float* Wf2 = (const float*)d_in[20];
  const float* bf2 = (const float*)d_in[21];

  char* ws = (char*)d_ws;
  short* wt_oa   = (short*)(ws + 0);          // 384x256 bf16
  short* wt_v    = (short*)(ws + 196608);
  short* wt_p    = (short*)(ws + 327680);     // frag-major packed
  short* wt_f1   = (short*)(ws + 458752);     // frag-major packed
  short* wt_f2   = (short*)(ws + 983040);     // frag-major packed
  short* qnb     = (short*)(ws + 1507328);    // 16384x256 bf16 (LN1, no pos)
  short* qa      = (short*)(ws + 18284544);   // 16384x256 bf16
  short* oabuf   = (short*)(ws + 26673152);   // 16384x288 bf16 (9.4 MB)
  short* vproj   = (short*)(ws + 45547520);   // 12600x256 bf16
  short* sampled = (short*)(ws + 51998720);   // 16384x256 bf16
  short* valbf   = (short*)(ws + 77164544);   // 12672x256 bf16
  float* outp = (float*)d_out;

  // 1. merged: weight convert/pack + value convert + LN1
  prep_all<<<9057, 256, 0, stream>>>(Wo, Wa, Wv, Wp, Wf1, Wf2,
                                     wt_oa, wt_v, wt_p, wt_f1, wt_f2,
                                     value, valbf, query, query_pos,
                                     g1, b1, qnb, qa);
  // 2. merged GEMMs: oa (768 blocks, bf16 out) + vproj (394 blocks)
  gemm_oa_v<<<1162, 256, 0, stream>>>(qa, wt_oa, bo, ba, oabuf,
                                      valbf, wt_v, bv, vproj);
  // 3. fused prep+gather -> sampled bf16
  deform_fused<<<2048, 256, 0, stream>>>(vproj, oabuf, ref_pts, sampled);
  // 4. merged Wp-GEMM + LN2 + MLP (64-row block, 128 KB LDS, no spill)
  wp_mlp<<<256, 1024, 0, stream>>>(sampled, wt_p, bp, qnb, query, g2, b2,
                                   wt_f1, bf1, wt_f2, bf2, outp);
}